// Round 8
// baseline (98.824 us; speedup 1.0000x reference)
//
#include <hip/hip_runtime.h>

#define NTYPES 50
#define NCATS  20
#define EDIM   64
#define BATCH  4
#define SEQL   256

// Blocks: 1024 LL (b,i) + 200 IT (b,t) + 4 IC (b) + 1 I0
#define LL_BLOCKS 1024
#define IT_BLOCKS 200
#define IC_BLOCKS 4
#define TOTAL_BLOCKS 1229

// ws float layout, every slot/counter on its own 128B (32-float) line:
//   value slot (target, gg) at ws[(target*32+gg)*32], gg = blk&31
//     targets: 0=ll, 1..4=int_b, 5=I0  -> lines 0..191
//   sub-counter gsub (blk&15) at line 192+gsub; top counter at line 208
#define SLOT(tgt, gg) (((tgt) * 32 + (gg)) * 32)
#define SUBC(gs)      ((192 + (gs)) * 32)
#define TOPC          (208 * 32)
#define WS_ZERO_BYTES ((208 * 32 + 1) * 4)

__device__ __forceinline__ float softplusf(float x) {
    return (x > 0.f) ? x + log1pf(__expf(-x)) : log1pf(__expf(x));
}

__device__ __forceinline__ float waveReduceSum(float v) {
    #pragma unroll
    for (int off = 32; off > 0; off >>= 1) v += __shfl_down(v, off, 64);
    return v;
}

__global__ __launch_bounds__(256) void hawkes_fused(
        const float* __restrict__ times,
        const int*   __restrict__ types,
        const int*   __restrict__ cats,
        const int*   __restrict__ Tp,
        const float* __restrict__ type_emb,
        const float* __restrict__ cat_emb,
        const float* __restrict__ amat,
        const float* __restrict__ bmat,
        const float* __restrict__ A,
        const float* __restrict__ P,
        const float* __restrict__ Bm,
        const float* __restrict__ Q,
        float* __restrict__ ws,
        float* __restrict__ out) {
    const int blk  = blockIdx.x;
    const int tid  = threadIdx.x;
    const int lane = tid & 63;
    const int wave = tid >> 6;
    const int e2   = lane & 31;   // float2 index over embedding dim
    const int sub  = lane >> 5;   // half-wave: which source residue
    const int gg   = blk & 31;    // value-slot spread group
    const int gs   = blk & 15;    // completion sub-group

    // Premultiplied tables (float4 = (coefA.x, coefA.y, -coefP.x, -coefP.y)):
    __shared__ float4 sAP4[NTYPES * 32];   // 25.6 KB
    __shared__ float4 sBQ4[NCATS * 32];    // 10.25 KB
    __shared__ float2 sSeq[SEQL];          //  2 KB  (time, bitcast(type|cat<<16))
    __shared__ float  red1[4];
    __shared__ float  sn[4][EDIM];
    __shared__ float  fin[192];
    __shared__ int    finflag;

    const float2* TE  = (const float2*)type_emb;
    const float2* CE  = (const float2*)cat_emb;
    const float2* A2p = (const float2*)A;
    const float2* P2p = (const float2*)P;
    const float2* B2p = (const float2*)Bm;
    const float2* Q2p = (const float2*)Q;
    const float2* am2 = (const float2*)amat;
    const float2* bm2 = (const float2*)bmat;

    if (blk < LL_BLOCKS) {
        // ---- log-likelihood term for event (b, i) ----
        const int b = blk >> 8, i = blk & 255;
        const int base = b * SEQL;
        const int t = types[base + i];
        const int c = (i > 0) ? cats[base + i - 1] : 0;
        const float ti = times[base + i];

        for (int s = tid; s < SEQL; s += 256)
            sSeq[s] = make_float2(times[base + s],
                                  __int_as_float(types[base + s] | (cats[base + s] << 16)));
        const float2 tep = TE[t * 32 + (tid & 31)];
        for (int j = tid; j < NTYPES * 32; j += 256) {   // j&31 == tid&31
            const int k = j >> 5, e = j & 31;
            const float2 f2 = TE[k * 32 + e];
            const float2 Av = A2p[(k * NTYPES + t) * 32 + e];
            const float2 Pv = P2p[(k * NTYPES + t) * 32 + e];
            const float tfx = tep.x * f2.x, tfy = tep.y * f2.y;
            sAP4[j] = make_float4(tfx * Av.x, tfy * Av.y, -tfx * Pv.x, -tfy * Pv.y);
        }
        const float2 cep = CE[c * 32 + (tid & 31)];
        for (int j = tid; j < NCATS * 32; j += 256) {
            const int cc = j >> 5, e = j & 31;
            const float2 g2 = CE[cc * 32 + e];
            const float2 Bv = B2p[(cc * NCATS + c) * 32 + e];
            const float2 Qv = Q2p[(cc * NCATS + c) * 32 + e];
            const float cgx = cep.x * g2.x, cgy = cep.y * g2.y;
            sBQ4[j] = make_float4(cgx * Bv.x, cgy * Bv.y, -cgx * Qv.x, -cgy * Qv.y);
        }
        __syncthreads();

        float2 acc = make_float2(0.f, 0.f);
        const int r = 2 * wave + sub;     // source residue mod 8
        #pragma unroll 2
        for (int s = r; s < i; s += 8) {
            const float2 sq = sSeq[s];
            const int    tc = __float_as_int(sq.y);
            const float  td = ti - sq.x;
            const float4 ap = sAP4[((tc & 0xffff) << 5) + e2];
            const float4 bq = sBQ4[((tc >> 16) << 5) + e2];
            acc.x += ap.x * __expf(ap.z * td) + bq.x * __expf(bq.z * td);
            acc.y += ap.y * __expf(ap.w * td) + bq.y * __expf(bq.w * td);
        }
        if (wave == 0 && sub == 0) {      // base term once; e2 covers all 64 dims
            const float2 av = am2[t * 32 + e2];
            const float2 tv = TE[t * 32 + e2];
            if (i == 0) {
                acc.x += softplusf(tv.x * av.x);
                acc.y += softplusf(tv.y * av.y);
            } else {
                const float2 bv = bm2[c * 32 + e2];
                acc.x += tv.x * (av.x + bv.x);
                acc.y += tv.y * (av.y + bv.y);
            }
        }
        const float rs = waveReduceSum(acc.x + acc.y);
        if (lane == 0) red1[wave] = rs;
        __syncthreads();
        if (tid == 0) {
            const float lam = red1[0] + red1[1] + red1[2] + red1[3];
            atomicAdd(&ws[SLOT(0, gg)], logf(lam + 1e-16f) + lam);
        }
    } else if (blk < LL_BLOCKS + IT_BLOCKS) {
        // ---- horizon integral, type channel, (b, t) ----
        const int bt = blk - LL_BLOCKS;
        const int b = bt / NTYPES, t = bt % NTYPES;
        const int base = b * SEQL;
        const float Tf = (float)Tp[0];
        for (int s = tid; s < SEQL; s += 256)
            sSeq[s] = make_float2(times[base + s], __int_as_float(types[base + s]));
        const float2 tep = TE[t * 32 + (tid & 31)];
        for (int j = tid; j < NTYPES * 32; j += 256) {
            const int k = j >> 5, e = j & 31;
            const float2 f2 = TE[k * 32 + e];
            const float2 Av = A2p[(k * NTYPES + t) * 32 + e];
            const float2 Pv = P2p[(k * NTYPES + t) * 32 + e];
            const float tfx = tep.x * f2.x, tfy = tep.y * f2.y;
            sAP4[j] = make_float4(tfx * Av.x, tfy * Av.y, -tfx * Pv.x, -tfy * Pv.y);
        }
        __syncthreads();
        float2 acc = make_float2(0.f, 0.f);
        const int r = 2 * wave + sub;
        #pragma unroll 4
        for (int s = r; s < SEQL; s += 8) {
            const float2 sq = sSeq[s];
            const float  td = Tf - sq.x;
            const float4 ap = sAP4[(__float_as_int(sq.y) << 5) + e2];
            acc.x += ap.x * __expf(ap.z * td);
            acc.y += ap.y * __expf(ap.w * td);
        }
        const float rs = waveReduceSum(acc.x + acc.y);
        if (lane == 0) red1[wave] = rs;
        __syncthreads();
        if (tid == 0)
            atomicAdd(&ws[SLOT(1 + b, gg)], red1[0] + red1[1] + red1[2] + red1[3]);
    } else if (blk < LL_BLOCKS + IT_BLOCKS + IC_BLOCKS) {
        // ---- horizon integral, category + base, per b (tiny; scalar form) ----
        const int b = blk - LL_BLOCKS - IT_BLOCKS;
        const int base = b * SEQL;
        const float Tf = (float)Tp[0];
        const int   lc = cats[base + SEQL - 1];
        const float ce = cat_emb[lc * EDIM + lane];
        float nacc = 0.f;
        #pragma unroll 4
        for (int s = wave; s < SEQL; s += 4) {
            const int   cs = cats[base + s];
            const float td = Tf - times[base + s];
            const float g2 = cat_emb[cs * EDIM + lane];
            const float Bk = Bm[(cs * NCATS + lc) * EDIM + lane];
            const float Qk = Q [(cs * NCATS + lc) * EDIM + lane];
            const float cg = ce * g2;
            nacc += cg * Bk * __expf(-cg * Qk * td);
        }
        sn[wave][lane] = nacc;
        __syncthreads();
        if (wave == 0) {
            const float n_e = sn[0][lane] + sn[1][lane] + sn[2][lane] + sn[3][lane];
            float TA = 0.f, TS = 0.f;
            for (int t = 0; t < NTYPES; ++t) {
                const float tv = type_emb[t * EDIM + lane];
                TA += tv * amat[t * EDIM + lane];
                TS += tv;
            }
            float term = TA + (bmat[lc * EDIM + lane] + n_e) * TS;
            term = waveReduceSum(term);
            if (lane == 0) atomicAdd(&ws[SLOT(1 + b, gg)], term);
        }
    } else {
        // ---- I0 ----
        float acc = 0.f;
        for (int t = wave; t < NTYPES; t += 4)
            acc += softplusf(type_emb[t * EDIM + lane] * amat[t * EDIM + lane]);
        const float rs = waveReduceSum(acc);
        if (lane == 0) red1[wave] = rs;
        __syncthreads();
        if (tid == 0)
            atomicAdd(&ws[SLOT(5, gg)], red1[0] + red1[1] + red1[2] + red1[3]);
    }

    // ---- hierarchical completion; atomics-only coherence ----
    if (tid == 0) {
        finflag = 0;
        __asm__ __volatile__("s_waitcnt vmcnt(0)" ::: "memory");
        const unsigned cnt_g = (unsigned)((TOTAL_BLOCKS + 15 - gs) >> 4);
        unsigned old = atomicAdd((unsigned int*)&ws[SUBC(gs)], 1u);
        if (old == cnt_g - 1u) {
            unsigned o2 = atomicAdd((unsigned int*)&ws[TOPC], 1u);
            if (o2 == 15u) finflag = 1;
        }
    }
    __syncthreads();
    if (finflag) {
        if (tid < 192) fin[tid] = atomicAdd(&ws[tid * 32], 0.f);
        __syncthreads();
        if (tid == 0) {
            float ll = 0.f, i0 = 0.f;
            for (int j = 0; j < 32; ++j) { ll += fin[j]; i0 += fin[160 + j]; }
            const float Tf = (float)Tp[0];
            float tot = 0.f;
            for (int b2 = 0; b2 < BATCH; ++b2) {
                float ib = 0.f;
                for (int j = 0; j < 32; ++j) ib += fin[(1 + b2) * 32 + j];
                tot += ib * (Tf - times[b2 * SEQL + SEQL - 1]) + i0 * times[b2 * SEQL];
            }
            out[0] = -(ll - tot);
        }
    }
}

extern "C" void kernel_launch(void* const* d_in, const int* in_sizes, int n_in,
                              void* d_out, int out_size, void* d_ws, size_t ws_size,
                              hipStream_t stream) {
    const float* times    = (const float*)d_in[0];
    const int*   types    = (const int*)  d_in[1];
    const int*   cats     = (const int*)  d_in[2];
    const int*   Tp       = (const int*)  d_in[3];
    const float* type_emb = (const float*)d_in[4];
    const float* cat_emb  = (const float*)d_in[5];
    const float* amat     = (const float*)d_in[6];
    const float* bmat     = (const float*)d_in[7];
    const float* A        = (const float*)d_in[8];
    const float* P        = (const float*)d_in[9];
    const float* Bm       = (const float*)d_in[10];
    const float* Q        = (const float*)d_in[11];
    float* out = (float*)d_out;
    float* ws  = (float*)d_ws;

    hipMemsetAsync(ws, 0, WS_ZERO_BYTES, stream);

    hawkes_fused<<<TOTAL_BLOCKS, 256, 0, stream>>>(times, types, cats, Tp,
                                                   type_emb, cat_emb, amat, bmat,
                                                   A, P, Bm, Q, ws, out);
}

// Round 9
// 98.432 us; speedup vs baseline: 1.0040x; 1.0040x over previous
//
#include <hip/hip_runtime.h>

#define NTYPES 50
#define NCATS  20
#define EDIM   64
#define BATCH  4
#define SEQL   256

// Blocks: 512 LL (b, pair{pr, 255-pr}) + 200 IT (b,t) + 4 IC (b) + 1 I0
#define LL_BLOCKS 512
#define IT_BLOCKS 200
#define IC_BLOCKS 4
#define TOTAL_BLOCKS 717

// ws float layout, every slot/counter on its own 128B (32-float) line:
//   value slot (target, g) at ws[(target*16+g)*32]; targets: 0=ll, 1..4=int_b, 5=I0
//   sub-counter g at ws[(96+g)*32]; top counter at ws[112*32]
#define SLOT(tgt, g) (((tgt) * 16 + (g)) * 32)
#define SUBC(g)      ((96 + (g)) * 32)
#define TOPC         (112 * 32)
#define WS_ZERO_BYTES ((112 * 32 + 1) * 4)

// Precomputed coefficient tables in ws (float4 units), 32KB-aligned:
//   APT[(k*NTYPES+t)*32+e2] = ( te.x*A.x*f.x, te.y*A.y*f.y,
//                               -log2e*te.x*P.x*f.x, -log2e*te.y*P.y*f.y )
//   BQT[(cs*NCATS+c)*32+e2] analogous with ce/Bm/Q/g.
#define APT_OFF4  2048                       // float4 index (byte 32768)
#define APT_N4    (NTYPES * NTYPES * 32)     // 80000
#define BQT_OFF4  (APT_OFF4 + APT_N4)        // 82048
#define BQT_N4    (NCATS * NCATS * 32)       // 12800
#define PREP_N4   (APT_N4 + BQT_N4)          // 92800
#define LOG2E     1.44269504088896340736f

__device__ __forceinline__ float softplusf(float x) {
    return (x > 0.f) ? x + log1pf(__expf(-x)) : log1pf(__expf(x));
}

__device__ __forceinline__ float waveReduceSum(float v) {
    #pragma unroll
    for (int off = 32; off > 0; off >>= 1) v += __shfl_down(v, off, 64);
    return v;
}

__global__ __launch_bounds__(256) void hawkes_prep(
        const float* __restrict__ type_emb,
        const float* __restrict__ cat_emb,
        const float* __restrict__ A,
        const float* __restrict__ P,
        const float* __restrict__ Bm,
        const float* __restrict__ Q,
        float* __restrict__ ws) {
    const int j = blockIdx.x * 256 + threadIdx.x;
    if (j >= PREP_N4) return;
    float4* wt = (float4*)ws;
    const float2* TE  = (const float2*)type_emb;
    const float2* CE  = (const float2*)cat_emb;
    if (j < APT_N4) {
        const int k  = j / (NTYPES * 32);
        const int r  = j % (NTYPES * 32);
        const int t  = r >> 5, e2 = r & 31;
        const float2 te = TE[t * 32 + e2];
        const float2 f  = TE[k * 32 + e2];
        const float2 Av = ((const float2*)A)[(k * NTYPES + t) * 32 + e2];
        const float2 Pv = ((const float2*)P)[(k * NTYPES + t) * 32 + e2];
        wt[APT_OFF4 + j] = make_float4(te.x * Av.x * f.x, te.y * Av.y * f.y,
                                       -LOG2E * te.x * Pv.x * f.x,
                                       -LOG2E * te.y * Pv.y * f.y);
    } else {
        const int j2 = j - APT_N4;
        const int cs = j2 / (NCATS * 32);
        const int r  = j2 % (NCATS * 32);
        const int c  = r >> 5, e2 = r & 31;
        const float2 ce = CE[c * 32 + e2];
        const float2 g  = CE[cs * 32 + e2];
        const float2 Bv = ((const float2*)Bm)[(cs * NCATS + c) * 32 + e2];
        const float2 Qv = ((const float2*)Q)[(cs * NCATS + c) * 32 + e2];
        wt[BQT_OFF4 + j2] = make_float4(ce.x * Bv.x * g.x, ce.y * Bv.y * g.y,
                                        -LOG2E * ce.x * Qv.x * g.x,
                                        -LOG2E * ce.y * Qv.y * g.y);
    }
}

__global__ __launch_bounds__(256) void hawkes_fused(
        const float* __restrict__ times,
        const int*   __restrict__ types,
        const int*   __restrict__ cats,
        const int*   __restrict__ Tp,
        const float* __restrict__ type_emb,
        const float* __restrict__ cat_emb,
        const float* __restrict__ amat,
        const float* __restrict__ bmat,
        const float* __restrict__ Bm,
        const float* __restrict__ Q,
        float* __restrict__ ws,
        float* __restrict__ out) {
    const int blk  = blockIdx.x;
    const int tid  = threadIdx.x;
    const int lane = tid & 63;
    const int wave = tid >> 6;
    const int e2   = lane & 31;   // float2 index over embedding dim
    const int sub  = lane >> 5;   // half-wave: which source residue
    const int g    = blk & 15;

    const float4* APT = ((const float4*)ws) + APT_OFF4;
    const float4* BQT = ((const float4*)ws) + BQT_OFF4;
    const float2* TE  = (const float2*)type_emb;
    const float2* am2 = (const float2*)amat;
    const float2* bm2 = (const float2*)bmat;

    __shared__ float2 sSeq[SEQL];          // (time, bitcast(type | cat<<16))
    __shared__ float  red1[4], red2[4];
    __shared__ float  sn[4][EDIM];
    __shared__ float  fin[96];
    __shared__ int    finflag;

    if (blk < LL_BLOCKS) {
        // ---- two events per block: i1 = pr (0..127), i2 = 255-pr (128..255) ----
        const int b  = blk >> 7;
        const int pr = blk & 127;
        const int i1 = pr, i2 = 255 - pr;
        const int base = b * SEQL;
        for (int s = tid; s < SEQL; s += 256)
            sSeq[s] = make_float2(times[base + s],
                                  __int_as_float(types[base + s] | (cats[base + s] << 16)));
        __syncthreads();
        const int   t1  = __float_as_int(sSeq[i1].y) & 0xffff;
        const int   t2  = __float_as_int(sSeq[i2].y) & 0xffff;
        const int   c1  = (i1 > 0) ? (__float_as_int(sSeq[i1 - 1].y) >> 16) : 0;
        const int   c2  = __float_as_int(sSeq[i2 - 1].y) >> 16;
        const float ti1 = sSeq[i1].x, ti2 = sSeq[i2].x;

        float2 acc1 = make_float2(0.f, 0.f), acc2 = make_float2(0.f, 0.f);
        const int r = 2 * wave + sub;          // source residue mod 8
        // sources s < i1: feed both events
        #pragma unroll 2
        for (int s = r; s < i1; s += 8) {
            const float2 sq = sSeq[s];
            const int    tc = __float_as_int(sq.y);
            const int    k  = tc & 0xffff, cs = tc >> 16;
            const float  td1 = ti1 - sq.x, td2 = ti2 - sq.x;
            const float4 ap1 = APT[(k * NTYPES + t1) * 32 + e2];
            const float4 bq1 = BQT[(cs * NCATS + c1) * 32 + e2];
            const float4 ap2 = APT[(k * NTYPES + t2) * 32 + e2];
            const float4 bq2 = BQT[(cs * NCATS + c2) * 32 + e2];
            acc1.x += ap1.x * exp2f(ap1.z * td1) + bq1.x * exp2f(bq1.z * td1);
            acc1.y += ap1.y * exp2f(ap1.w * td1) + bq1.y * exp2f(bq1.w * td1);
            acc2.x += ap2.x * exp2f(ap2.z * td2) + bq2.x * exp2f(bq2.z * td2);
            acc2.y += ap2.y * exp2f(ap2.w * td2) + bq2.y * exp2f(bq2.w * td2);
        }
        // sources i1 <= s < i2: event2 only
        const int d  = i1 - r;
        const int s0 = r + ((d > 0) ? (((d + 7) >> 3) << 3) : 0);
        #pragma unroll 2
        for (int s = s0; s < i2; s += 8) {
            const float2 sq = sSeq[s];
            const int    tc = __float_as_int(sq.y);
            const int    k  = tc & 0xffff, cs = tc >> 16;
            const float  td2 = ti2 - sq.x;
            const float4 ap2 = APT[(k * NTYPES + t2) * 32 + e2];
            const float4 bq2 = BQT[(cs * NCATS + c2) * 32 + e2];
            acc2.x += ap2.x * exp2f(ap2.z * td2) + bq2.x * exp2f(bq2.z * td2);
            acc2.y += ap2.y * exp2f(ap2.w * td2) + bq2.y * exp2f(bq2.w * td2);
        }
        // base terms: added exactly once (sub==0 lanes cover all 64 e via float2)
        if (wave == 0 && sub == 0) {
            const float2 av = am2[t1 * 32 + e2];
            const float2 tv = TE[t1 * 32 + e2];
            if (i1 == 0) {
                acc1.x += softplusf(tv.x * av.x);
                acc1.y += softplusf(tv.y * av.y);
            } else {
                const float2 bv = bm2[c1 * 32 + e2];
                acc1.x += tv.x * (av.x + bv.x);
                acc1.y += tv.y * (av.y + bv.y);
            }
        } else if (wave == 1 && sub == 0) {
            const float2 av = am2[t2 * 32 + e2];
            const float2 bv = bm2[c2 * 32 + e2];
            const float2 tv = TE[t2 * 32 + e2];
            acc2.x += tv.x * (av.x + bv.x);
            acc2.y += tv.y * (av.y + bv.y);
        }
        const float r1 = waveReduceSum(acc1.x + acc1.y);
        const float r2 = waveReduceSum(acc2.x + acc2.y);
        if (lane == 0) { red1[wave] = r1; red2[wave] = r2; }
        __syncthreads();
        if (tid == 0) {
            const float lam1 = red1[0] + red1[1] + red1[2] + red1[3];
            const float lam2 = red2[0] + red2[1] + red2[2] + red2[3];
            atomicAdd(&ws[SLOT(0, g)], logf(lam1 + 1e-16f) + lam1
                                     + logf(lam2 + 1e-16f) + lam2);
        }
    } else if (blk < LL_BLOCKS + IT_BLOCKS) {
        // ---- horizon integral, type channel, (b, t) ----
        const int bt = blk - LL_BLOCKS;
        const int b = bt / NTYPES, t = bt % NTYPES;
        const int base = b * SEQL;
        for (int s = tid; s < SEQL; s += 256)
            sSeq[s] = make_float2(times[base + s], __int_as_float(types[base + s]));
        __syncthreads();
        const float Tf = (float)Tp[0];
        float2 acc = make_float2(0.f, 0.f);
        const int r = 2 * wave + sub;
        #pragma unroll 4
        for (int s = r; s < SEQL; s += 8) {
            const float2 sq = sSeq[s];
            const int    k  = __float_as_int(sq.y);
            const float  td = Tf - sq.x;
            const float4 ap = APT[(k * NTYPES + t) * 32 + e2];
            acc.x += ap.x * exp2f(ap.z * td);
            acc.y += ap.y * exp2f(ap.w * td);
        }
        const float rr = waveReduceSum(acc.x + acc.y);
        if (lane == 0) red1[wave] = rr;
        __syncthreads();
        if (tid == 0)
            atomicAdd(&ws[SLOT(1 + b, g)], red1[0] + red1[1] + red1[2] + red1[3]);
    } else if (blk < LL_BLOCKS + IT_BLOCKS + IC_BLOCKS) {
        // ---- horizon integral, category + base, per b (tiny; scalar form) ----
        const int b = blk - LL_BLOCKS - IT_BLOCKS;
        const int base = b * SEQL;
        const float Tf = (float)Tp[0];
        const int   lc = cats[base + SEQL - 1];
        const float* BQTf = (const float*)BQT;
        float nacc = 0.f;
        #pragma unroll 4
        for (int s = wave; s < SEQL; s += 4) {
            const int   cs = cats[base + s];
            const float td = Tf - times[base + s];
            const int   i4 = (cs * NCATS + lc) * 32 + (lane >> 1);
            const float Bk = BQTf[i4 * 4 + (lane & 1)];
            const float Qk = BQTf[i4 * 4 + 2 + (lane & 1)];
            nacc += Bk * exp2f(Qk * td);
        }
        sn[wave][lane] = nacc;
        __syncthreads();
        if (wave == 0) {
            const float n_e = sn[0][lane] + sn[1][lane] + sn[2][lane] + sn[3][lane];
            float TA = 0.f, TS = 0.f;
            for (int t = 0; t < NTYPES; ++t) {
                const float tv = type_emb[t * EDIM + lane];
                TA += tv * amat[t * EDIM + lane];
                TS += tv;
            }
            float term = TA + (bmat[lc * EDIM + lane] + n_e) * TS;
            term = waveReduceSum(term);
            if (lane == 0) atomicAdd(&ws[SLOT(1 + b, g)], term);
        }
    } else {
        // ---- I0 ----
        float acc = 0.f;
        for (int t = wave; t < NTYPES; t += 4)
            acc += softplusf(type_emb[t * EDIM + lane] * amat[t * EDIM + lane]);
        const float rr = waveReduceSum(acc);
        if (lane == 0) red1[wave] = rr;
        __syncthreads();
        if (tid == 0)
            atomicAdd(&ws[SLOT(5, g)], red1[0] + red1[1] + red1[2] + red1[3]);
    }

    // ---- hierarchical completion; atomics-only coherence ----
    if (tid == 0) {
        finflag = 0;
        __asm__ __volatile__("s_waitcnt vmcnt(0)" ::: "memory");
        const unsigned cnt_g = (unsigned)((TOTAL_BLOCKS + 15 - g) >> 4);
        unsigned old = atomicAdd((unsigned int*)&ws[SUBC(g)], 1u);
        if (old == cnt_g - 1u) {
            unsigned o2 = atomicAdd((unsigned int*)&ws[TOPC], 1u);
            if (o2 == 15u) finflag = 1;
        }
    }
    __syncthreads();
    if (finflag) {
        if (tid < 96) fin[tid] = atomicAdd(&ws[tid * 32], 0.f);
        __syncthreads();
        if (tid == 0) {
            float ll = 0.f, i0 = 0.f;
            for (int j = 0; j < 16; ++j) { ll += fin[j]; i0 += fin[80 + j]; }
            const float Tf = (float)Tp[0];
            float tot = 0.f;
            for (int b2 = 0; b2 < BATCH; ++b2) {
                float ib = 0.f;
                for (int j = 0; j < 16; ++j) ib += fin[(1 + b2) * 16 + j];
                tot += ib * (Tf - times[b2 * SEQL + SEQL - 1]) + i0 * times[b2 * SEQL];
            }
            out[0] = -(ll - tot);
        }
    }
}

extern "C" void kernel_launch(void* const* d_in, const int* in_sizes, int n_in,
                              void* d_out, int out_size, void* d_ws, size_t ws_size,
                              hipStream_t stream) {
    const float* times    = (const float*)d_in[0];
    const int*   types    = (const int*)  d_in[1];
    const int*   cats     = (const int*)  d_in[2];
    const int*   Tp       = (const int*)  d_in[3];
    const float* type_emb = (const float*)d_in[4];
    const float* cat_emb  = (const float*)d_in[5];
    const float* amat     = (const float*)d_in[6];
    const float* bmat     = (const float*)d_in[7];
    const float* A        = (const float*)d_in[8];
    const float* P        = (const float*)d_in[9];
    const float* Bm       = (const float*)d_in[10];
    const float* Q        = (const float*)d_in[11];
    float* out = (float*)d_out;
    float* ws  = (float*)d_ws;

    hipMemsetAsync(ws, 0, WS_ZERO_BYTES, stream);

    hawkes_prep<<<(PREP_N4 + 255) / 256, 256, 0, stream>>>(type_emb, cat_emb,
                                                           A, P, Bm, Q, ws);

    hawkes_fused<<<TOTAL_BLOCKS, 256, 0, stream>>>(times, types, cats, Tp,
                                                   type_emb, cat_emb, amat, bmat,
                                                   Bm, Q, ws, out);
}

// Round 10
// 96.774 us; speedup vs baseline: 1.0212x; 1.0171x over previous
//
#include <hip/hip_runtime.h>

#define NTYPES 50
#define NCATS  20
#define EDIM   64
#define BATCH  4
#define SEQL   256

// Blocks: 512 LL (b, pair{pr, 255-pr}) + 200 IT (b,t) + 4 IC (b) + 1 I0
#define LL_BLOCKS 512
#define IT_BLOCKS 200
#define IC_BLOCKS 4
#define TOTAL_BLOCKS 717

// ws float layout, every slot/counter on its own 128B (32-float) line:
//   value slot (target, g) at ws[(target*16+g)*32]; targets: 0=ll, 1..4=int_b, 5=I0
//   sub-counter g at ws[(96+g)*32]; top counter at ws[112*32]
#define SLOT(tgt, g) (((tgt) * 16 + (g)) * 32)
#define SUBC(g)      ((96 + (g)) * 32)
#define TOPC         (112 * 32)
#define WS_ZERO_BYTES ((112 * 32 + 1) * 4)

__device__ __forceinline__ float softplusf(float x) {
    return (x > 0.f) ? x + log1pf(__expf(-x)) : log1pf(__expf(x));
}

__device__ __forceinline__ float waveReduceSum(float v) {
    #pragma unroll
    for (int off = 32; off > 0; off >>= 1) v += __shfl_down(v, off, 64);
    return v;
}

__global__ __launch_bounds__(256) void hawkes_fused(
        const float* __restrict__ times,
        const int*   __restrict__ types,
        const int*   __restrict__ cats,
        const int*   __restrict__ Tp,
        const float* __restrict__ type_emb,
        const float* __restrict__ cat_emb,
        const float* __restrict__ amat,
        const float* __restrict__ bmat,
        const float* __restrict__ A,
        const float* __restrict__ P,
        const float* __restrict__ Bm,
        const float* __restrict__ Q,
        float* __restrict__ ws,
        float* __restrict__ out) {
    const int blk  = blockIdx.x;
    const int tid  = threadIdx.x;
    const int lane = tid & 63;
    const int wave = tid >> 6;
    const int g    = blk & 15;

    __shared__ float red1[4], red2[4];
    __shared__ float sn[4][EDIM];
    __shared__ float fin[96];
    __shared__ int   finflag;

    if (blk < LL_BLOCKS) {
        // ---- two events per block: i1 = pr (0..127), i2 = 255-pr (128..255) ----
        const int b  = blk >> 7;
        const int pr = blk & 127;
        const int i1 = pr, i2 = 255 - pr;
        const int base = b * SEQL;
        const int t1 = types[base + i1], t2 = types[base + i2];
        const int c2 = cats[base + i2 - 1];
        const int c1 = (i1 > 0) ? cats[base + i1 - 1] : 0;
        const float te1 = type_emb[t1 * EDIM + lane];
        const float te2 = type_emb[t2 * EDIM + lane];
        const float ce1 = cat_emb[c1 * EDIM + lane];
        const float ce2 = cat_emb[c2 * EDIM + lane];
        const float ti1 = times[base + i1], ti2 = times[base + i2];

        float acc1 = 0.f, acc2 = 0.f;
        // sources s ≡ wave (mod 4); s < i1 feeds both events, s in [i1,i2) only ev2
        #pragma unroll 4
        for (int s = wave; s < i1; s += 4) {
            const int   k  = types[base + s];
            const int   cs = cats [base + s];
            const float ts = times[base + s];
            const float f  = type_emb[k  * EDIM + lane];
            const float gg = cat_emb [cs * EDIM + lane];
            const float A1 = A [(k  * NTYPES + t1) * EDIM + lane];
            const float P1 = P [(k  * NTYPES + t1) * EDIM + lane];
            const float B1 = Bm[(cs * NCATS  + c1) * EDIM + lane];
            const float Q1 = Q [(cs * NCATS  + c1) * EDIM + lane];
            const float A2 = A [(k  * NTYPES + t2) * EDIM + lane];
            const float P2 = P [(k  * NTYPES + t2) * EDIM + lane];
            const float B2 = Bm[(cs * NCATS  + c2) * EDIM + lane];
            const float Q2 = Q [(cs * NCATS  + c2) * EDIM + lane];
            const float td1 = ti1 - ts, td2 = ti2 - ts;
            const float tf1 = te1 * f, cg1 = ce1 * gg;
            const float tf2 = te2 * f, cg2 = ce2 * gg;
            acc1 += tf1 * A1 * __expf(-tf1 * P1 * td1) + cg1 * B1 * __expf(-cg1 * Q1 * td1);
            acc2 += tf2 * A2 * __expf(-tf2 * P2 * td2) + cg2 * B2 * __expf(-cg2 * Q2 * td2);
        }
        const int n1 = (i1 > wave) ? ((i1 - wave + 3) >> 2) : 0;
        #pragma unroll 4
        for (int s = wave + 4 * n1; s < i2; s += 4) {
            const int   k  = types[base + s];
            const int   cs = cats [base + s];
            const float ts = times[base + s];
            const float f  = type_emb[k  * EDIM + lane];
            const float gg = cat_emb [cs * EDIM + lane];
            const float A2 = A [(k  * NTYPES + t2) * EDIM + lane];
            const float P2 = P [(k  * NTYPES + t2) * EDIM + lane];
            const float B2 = Bm[(cs * NCATS  + c2) * EDIM + lane];
            const float Q2 = Q [(cs * NCATS  + c2) * EDIM + lane];
            const float td2 = ti2 - ts;
            const float tf2 = te2 * f, cg2 = ce2 * gg;
            acc2 += tf2 * A2 * __expf(-tf2 * P2 * td2) + cg2 * B2 * __expf(-cg2 * Q2 * td2);
        }
        if (wave == 0) {
            if (i1 == 0) acc1 += softplusf(te1 * amat[t1 * EDIM + lane]);
            else         acc1 += te1 * (amat[t1 * EDIM + lane] + bmat[c1 * EDIM + lane]);
        } else if (wave == 1) {
            acc2 += te2 * (amat[t2 * EDIM + lane] + bmat[c2 * EDIM + lane]);
        }
        const float r1 = waveReduceSum(acc1);
        const float r2 = waveReduceSum(acc2);
        if (lane == 0) { red1[wave] = r1; red2[wave] = r2; }
        __syncthreads();
        if (tid == 0) {
            const float lam1 = red1[0] + red1[1] + red1[2] + red1[3];
            const float lam2 = red2[0] + red2[1] + red2[2] + red2[3];
            atomicAdd(&ws[SLOT(0, g)], logf(lam1 + 1e-16f) + lam1
                                     + logf(lam2 + 1e-16f) + lam2);
        }
    } else if (blk < LL_BLOCKS + IT_BLOCKS) {
        // ---- horizon integral, type channel, (b, t) ----
        const int bt = blk - LL_BLOCKS;
        const int b = bt / NTYPES, t = bt % NTYPES;
        const int base = b * SEQL;
        const float Tf = (float)Tp[0];
        const float te = type_emb[t * EDIM + lane];
        float acc = 0.f;
        #pragma unroll 4
        for (int s = wave; s < SEQL; s += 4) {
            const int   k  = types[base + s];
            const float td = Tf - times[base + s];
            const float f  = type_emb[k * EDIM + lane];
            const float Ak = A[(k * NTYPES + t) * EDIM + lane];
            const float Pk = P[(k * NTYPES + t) * EDIM + lane];
            const float tf = te * f;
            acc += tf * Ak * __expf(-tf * Pk * td);
        }
        const float r = waveReduceSum(acc);
        if (lane == 0) red1[wave] = r;
        __syncthreads();
        if (tid == 0)
            atomicAdd(&ws[SLOT(1 + b, g)], red1[0] + red1[1] + red1[2] + red1[3]);
    } else if (blk < LL_BLOCKS + IT_BLOCKS + IC_BLOCKS) {
        // ---- horizon integral, category + base, per b ----
        const int b = blk - LL_BLOCKS - IT_BLOCKS;
        const int base = b * SEQL;
        const float Tf = (float)Tp[0];
        const int   lc = cats[base + SEQL - 1];
        const float ce = cat_emb[lc * EDIM + lane];
        float nacc = 0.f;
        #pragma unroll 4
        for (int s = wave; s < SEQL; s += 4) {
            const int   cs = cats[base + s];
            const float td = Tf - times[base + s];
            const float gg = cat_emb[cs * EDIM + lane];
            const float Bk = Bm[(cs * NCATS + lc) * EDIM + lane];
            const float Qk = Q [(cs * NCATS + lc) * EDIM + lane];
            const float cg = ce * gg;
            nacc += cg * Bk * __expf(-cg * Qk * td);
        }
        sn[wave][lane] = nacc;
        __syncthreads();
        if (wave == 0) {
            const float n_e = sn[0][lane] + sn[1][lane] + sn[2][lane] + sn[3][lane];
            float TA = 0.f, TS = 0.f;
            for (int t = 0; t < NTYPES; ++t) {
                const float tv = type_emb[t * EDIM + lane];
                TA += tv * amat[t * EDIM + lane];
                TS += tv;
            }
            float term = TA + (bmat[lc * EDIM + lane] + n_e) * TS;
            term = waveReduceSum(term);
            if (lane == 0) atomicAdd(&ws[SLOT(1 + b, g)], term);
        }
    } else {
        // ---- I0 ----
        float acc = 0.f;
        for (int t = wave; t < NTYPES; t += 4)
            acc += softplusf(type_emb[t * EDIM + lane] * amat[t * EDIM + lane]);
        const float r = waveReduceSum(acc);
        if (lane == 0) red1[wave] = r;
        __syncthreads();
        if (tid == 0)
            atomicAdd(&ws[SLOT(5, g)], red1[0] + red1[1] + red1[2] + red1[3]);
    }

    // ---- hierarchical completion; atomics-only coherence ----
    if (tid == 0) {
        finflag = 0;
        __asm__ __volatile__("s_waitcnt vmcnt(0)" ::: "memory");
        const unsigned cnt_g = (unsigned)((TOTAL_BLOCKS + 15 - g) >> 4);
        unsigned old = atomicAdd((unsigned int*)&ws[SUBC(g)], 1u);
        if (old == cnt_g - 1u) {
            unsigned o2 = atomicAdd((unsigned int*)&ws[TOPC], 1u);
            if (o2 == 15u) finflag = 1;
        }
    }
    __syncthreads();
    if (finflag) {
        if (tid < 96) fin[tid] = atomicAdd(&ws[tid * 32], 0.f);
        __syncthreads();
        if (tid == 0) {
            float ll = 0.f, i0 = 0.f;
            for (int j = 0; j < 16; ++j) { ll += fin[j]; i0 += fin[80 + j]; }
            const float Tf = (float)Tp[0];
            float tot = 0.f;
            for (int b2 = 0; b2 < BATCH; ++b2) {
                float ib = 0.f;
                for (int j = 0; j < 16; ++j) ib += fin[(1 + b2) * 16 + j];
                tot += ib * (Tf - times[b2 * SEQL + SEQL - 1]) + i0 * times[b2 * SEQL];
            }
            out[0] = -(ll - tot);
        }
    }
}

extern "C" void kernel_launch(void* const* d_in, const int* in_sizes, int n_in,
                              void* d_out, int out_size, void* d_ws, size_t ws_size,
                              hipStream_t stream) {
    const float* times    = (const float*)d_in[0];
    const int*   types    = (const int*)  d_in[1];
    const int*   cats     = (const int*)  d_in[2];
    const int*   Tp       = (const int*)  d_in[3];
    const float* type_emb = (const float*)d_in[4];
    const float* cat_emb  = (const float*)d_in[5];
    const float* amat     = (const float*)d_in[6];
    const float* bmat     = (const float*)d_in[7];
    const float* A        = (const float*)d_in[8];
    const float* P        = (const float*)d_in[9];
    const float* Bm       = (const float*)d_in[10];
    const float* Q        = (const float*)d_in[11];
    float* out = (float*)d_out;
    float* ws  = (float*)d_ws;

    hipMemsetAsync(ws, 0, WS_ZERO_BYTES, stream);

    hawkes_fused<<<TOTAL_BLOCKS, 256, 0, stream>>>(times, types, cats, Tp,
                                                   type_emb, cat_emb, amat, bmat,
                                                   A, P, Bm, Q, ws, out);
}